// Round 7
// baseline (256.334 us; speedup 1.0000x reference)
//
#include <hip/hip_runtime.h>

#define BSEG   64
#define LATENT 256
#define NBF    1024            // fused grid: 4 blocks/CU (round-3-proven launchable)
#define ITERS  4               // 1M float4 / (NBF*256), guarded
#define NGRP   32              // barrier tree: 32 groups of 32 blocks
#define SCALE_F   1.0995116e12f          // 2^40 (e <= 1 after block-max sub)
#define INV_SCALE 9.094947017729282e-13 // 2^-40 (double)
#define ENC_NEG_INF 0x007FFFFFu          // enc_f32(-INFINITY)

// Monotone order-preserving f32 -> u32 encoding (for native integer atomicMax).
__device__ __forceinline__ unsigned enc_f32(float x) {
    unsigned u = __float_as_uint(x);
    return (u & 0x80000000u) ? ~u : (u | 0x80000000u);
}
__device__ __forceinline__ float dec_f32(unsigned e) {
    unsigned u = (e & 0x80000000u) ? (e & 0x7FFFFFFFu) : ~e;
    return __uint_as_float(u);
}

// Tree grid barrier: 32 group counters -> root -> release flag.
// st layout (u32, 16-stride = 64B pad): st[g*16] g=0..31 group counters,
// st[32*16] root, st[33*16] flag. Requires all NBF blocks co-resident.
__device__ __forceinline__ void gbar(unsigned* st) {
    __syncthreads();                       // all block lanes drained their stores
    if (threadIdx.x == 0) {
        __threadfence();                   // agent fence: L2 writeback (release)
        unsigned grp = blockIdx.x >> 5;    // 32 blocks per group
        unsigned old = __hip_atomic_fetch_add(&st[grp * 16], 1u,
                                              __ATOMIC_ACQ_REL, __HIP_MEMORY_SCOPE_AGENT);
        if (old == 31u) {                  // last of the group
            unsigned r = __hip_atomic_fetch_add(&st[NGRP * 16], 1u,
                                               __ATOMIC_ACQ_REL, __HIP_MEMORY_SCOPE_AGENT);
            if (r == NGRP - 1u)
                __hip_atomic_store(&st[(NGRP + 1) * 16], 1u,
                                   __ATOMIC_RELEASE, __HIP_MEMORY_SCOPE_AGENT);
        }
        while (__hip_atomic_load(&st[(NGRP + 1) * 16], __ATOMIC_ACQUIRE,
                                 __HIP_MEMORY_SCOPE_AGENT) == 0u)
            __builtin_amdgcn_s_sleep(8);
        __threadfence();                   // acquire: invalidate stale lines
    }
    __syncthreads();
}

#define BAR_U32S ((NGRP + 2) * 16)         // u32s per barrier instance

// A: uncertainty[b] = 128*log(2*pi*e) + sum_k log(std).
// Block 0 also re-zeros both barrier instances (graph-replay / poison safe).
__global__ __launch_bounds__(256) void k_unc(const float* __restrict__ pstd,
                                             float* __restrict__ unc,
                                             float* __restrict__ out_unc,
                                             unsigned* __restrict__ bar) {
    if (blockIdx.x == 0) {
        for (int i = threadIdx.x; i < 2 * BAR_U32S; i += 256) bar[i] = 0u;
    }
    int b = blockIdx.x;
    float v = logf(pstd[b * LATENT + threadIdx.x]);
#pragma unroll
    for (int off = 32; off > 0; off >>= 1) v += __shfl_down(v, off, 64);
    __shared__ float part[4];
    int lane = threadIdx.x & 63, wv = threadIdx.x >> 6;
    if (lane == 0) part[wv] = v;
    __syncthreads();
    if (threadIdx.x == 0) {
        float s = part[0] + part[1] + part[2] + part[3];
        float u = 128.0f * 2.83787706640934548f + s;
        unc[b]     = u;
        out_unc[b] = u;
    }
}

// Fused: priority + block-online-softmax + tree barrier + combine + normalize.
// Each thread's 16 (p,b) pairs live in registers across both barriers.
__global__ __launch_bounds__(256, 4) void k_fused(
    const float* __restrict__ coh, const int* __restrict__ batch,
    const float* __restrict__ unc,
    float* __restrict__ bmax_t,          // [BSEG][NBF] transposed block maxima
    float* __restrict__ bsum_t,          // [BSEG][NBF] transposed block sums
    float* __restrict__ maxf, float* __restrict__ rsum,
    unsigned* __restrict__ bar,
    float* __restrict__ pri, float* __restrict__ nrm, int n) {
    __shared__ float    unc_s[BSEG];
    __shared__ unsigned max_s[4][BSEG];
    __shared__ unsigned long long sum_s[4][BSEG];
    __shared__ float m_s[BSEG];
    __shared__ float r_s[BSEG];

    int t = threadIdx.x, wv = t >> 6;
    if (t < BSEG) {
        unc_s[t] = unc[t];
#pragma unroll
        for (int w = 0; w < 4; ++w) { max_s[w][t] = ENC_NEG_INF; sum_s[w][t] = 0ull; }
    }
    __syncthreads();

    int gid = blockIdx.x * 256 + t;
    int nv  = n >> 2;

    // ---- Phase 1: priority + per-block max ----
    float4 pr[ITERS];
    int4   bi[ITERS];
#pragma unroll
    for (int u = 0; u < ITERS; ++u) {
        int i = gid + u * (NBF * 256);
        if (i < nv) {
            float4 cv = ((const float4*)coh)[i];
            int4   bv = ((const int4*)batch)[i];
            float4 pv;
            pv.x = cv.x * unc_s[bv.x];
            pv.y = cv.y * unc_s[bv.y];
            pv.z = cv.z * unc_s[bv.z];
            pv.w = cv.w * unc_s[bv.w];
            pr[u] = pv; bi[u] = bv;
            ((float4*)pri)[i] = pv;
            unsigned e0 = enc_f32(pv.x); if (e0 > max_s[wv][bv.x]) atomicMax(&max_s[wv][bv.x], e0);
            unsigned e1 = enc_f32(pv.y); if (e1 > max_s[wv][bv.y]) atomicMax(&max_s[wv][bv.y], e1);
            unsigned e2 = enc_f32(pv.z); if (e2 > max_s[wv][bv.z]) atomicMax(&max_s[wv][bv.z], e2);
            unsigned e3 = enc_f32(pv.w); if (e3 > max_s[wv][bv.w]) atomicMax(&max_s[wv][bv.w], e3);
        } else {
            bi[u].x = -1;
        }
    }
    // scalar tail (n % 4), block 0 only
    float p_t = 0.0f; int b_t = -1;
    if (blockIdx.x == 0) {
        int rem = n - (nv << 2);
        if (t < rem) {
            int i = (nv << 2) + t;
            b_t = batch[i];
            p_t = coh[i] * unc_s[b_t];
            pri[i] = p_t;
            atomicMax(&max_s[wv][b_t], enc_f32(p_t));
        }
    }
    __syncthreads();
    if (t < BSEG) {
        unsigned m = max(max(max_s[0][t], max_s[1][t]), max(max_s[2][t], max_s[3][t]));
        float mf = dec_f32(m);
        m_s[t] = mf;
        bmax_t[t * NBF + blockIdx.x] = mf;
    }
    __syncthreads();

    // ---- Phase 1b: block partial sums exp(p - m_blk) in fixed-point u64 ----
#pragma unroll
    for (int u = 0; u < ITERS; ++u) {
        if (bi[u].x >= 0) {
            int4 bv = bi[u]; float4 pv = pr[u];
            atomicAdd(&sum_s[wv][bv.x], (unsigned long long)(expf(pv.x - m_s[bv.x]) * SCALE_F));
            atomicAdd(&sum_s[wv][bv.y], (unsigned long long)(expf(pv.y - m_s[bv.y]) * SCALE_F));
            atomicAdd(&sum_s[wv][bv.z], (unsigned long long)(expf(pv.z - m_s[bv.z]) * SCALE_F));
            atomicAdd(&sum_s[wv][bv.w], (unsigned long long)(expf(pv.w - m_s[bv.w]) * SCALE_F));
        }
    }
    if (b_t >= 0)
        atomicAdd(&sum_s[wv][b_t], (unsigned long long)(expf(p_t - m_s[b_t]) * SCALE_F));
    __syncthreads();
    if (t < BSEG) {
        unsigned long long tot = sum_s[0][t] + sum_s[1][t] + sum_s[2][t] + sum_s[3][t];
        bsum_t[t * NBF + blockIdx.x] = (float)((double)tot * INV_SCALE);
    }

    gbar(bar);                       // ---- barrier 1 ----

    // ---- Combine: blocks 0..63 merge one segment each ----
    if (blockIdx.x < BSEG) {
        int s = blockIdx.x;
        const float* bm = bmax_t + s * NBF;
        const float* bs = bsum_t + s * NBF;
        float m = -INFINITY;
        for (int i = t; i < NBF; i += 256) m = fmaxf(m, bm[i]);
#pragma unroll
        for (int off = 32; off > 0; off >>= 1) m = fmaxf(m, __shfl_down(m, off, 64));
        __shared__ float cpart[4];
        if ((t & 63) == 0) cpart[t >> 6] = m;
        __syncthreads();
        float m_g = fmaxf(fmaxf(cpart[0], cpart[1]), fmaxf(cpart[2], cpart[3]));
        double acc = 0.0;
        for (int i = t; i < NBF; i += 256) {
            float d = bm[i] - m_g;
            if (d < -100.0f) d = -100.0f;   // -inf-(-inf) NaN guard; bs=0 there
            acc += (double)bs[i] * (double)expf(d);
        }
#pragma unroll
        for (int off = 32; off > 0; off >>= 1) acc += __shfl_down(acc, off, 64);
        __shared__ double cpart2[4];
        if ((t & 63) == 0) cpart2[t >> 6] = acc;
        __syncthreads();
        if (t == 0) {
            double tot = cpart2[0] + cpart2[1] + cpart2[2] + cpart2[3];
            maxf[s] = m_g;
            rsum[s] = (tot > 0.0) ? (float)(1.0 / tot) : 0.0f;
        }
    }

    gbar(bar + BAR_U32S);            // ---- barrier 2 ----

    // ---- Phase 2: normalized straight from registers ----
    if (t < BSEG) { m_s[t] = maxf[t]; r_s[t] = rsum[t]; }
    __syncthreads();
#pragma unroll
    for (int u = 0; u < ITERS; ++u) {
        int i = gid + u * (NBF * 256);
        if (bi[u].x >= 0) {
            int4 bv = bi[u]; float4 pv = pr[u];
            float4 ov;
            ov.x = expf(pv.x - m_s[bv.x]) * r_s[bv.x];
            ov.y = expf(pv.y - m_s[bv.y]) * r_s[bv.y];
            ov.z = expf(pv.z - m_s[bv.z]) * r_s[bv.z];
            ov.w = expf(pv.w - m_s[bv.w]) * r_s[bv.w];
            ((float4*)nrm)[i] = ov;
        }
    }
    if (b_t >= 0)
        nrm[(nv << 2) + t] = expf(p_t - m_s[b_t]) * r_s[b_t];
}

extern "C" void kernel_launch(void* const* d_in, const int* in_sizes, int n_in,
                              void* d_out, int out_size, void* d_ws, size_t ws_size,
                              hipStream_t stream) {
    const float* coh   = (const float*)d_in[0];
    // d_in[1] = posterior_mean (unused by the reference outputs)
    const float* pstd  = (const float*)d_in[2];
    const int*   batch = (const int*)d_in[3];
    int n = in_sizes[0];

    float* out     = (float*)d_out;
    float* out_pri = out;
    float* out_nrm = out + n;
    float* out_unc = out + 2 * (size_t)n;

    // ws layout (bytes):
    // [0,256)     unc
    // [256,512)   maxf
    // [512,768)   rsum
    // [4096, 4096 + 2*BAR_U32S*4)  barrier state (2 instances)
    // [16384, +NBF*64*4)           bmax_t (transposed [seg][block])
    // [+NBF*64*4, +2*NBF*64*4)     bsum_t
    float*    ws_unc  = (float*)d_ws;
    float*    ws_maxf = (float*)((char*)d_ws + 256);
    float*    ws_rsum = (float*)((char*)d_ws + 512);
    unsigned* ws_bar  = (unsigned*)((char*)d_ws + 4096);
    float*    ws_bmax = (float*)((char*)d_ws + 16384);
    float*    ws_bsum = (float*)((char*)d_ws + 16384 + (size_t)NBF * BSEG * 4);

    k_unc<<<BSEG, 256, 0, stream>>>(pstd, ws_unc, out_unc, ws_bar);

    void* args[] = {(void*)&coh, (void*)&batch, (void*)&ws_unc,
                    (void*)&ws_bmax, (void*)&ws_bsum,
                    (void*)&ws_maxf, (void*)&ws_rsum, (void*)&ws_bar,
                    (void*)&out_pri, (void*)&out_nrm, (void*)&n};
    hipError_t err = hipLaunchCooperativeKernel((const void*)k_fused, dim3(NBF),
                                                dim3(256), args, 0, stream);
    if (err != hipSuccess) {
        // Fallback: plain launch. 1024 blocks at 4 blocks/CU (launch_bounds)
        // <= 256 CU capacity -> all blocks resident; barrier remains safe.
        k_fused<<<NBF, 256, 0, stream>>>(coh, batch, ws_unc, ws_bmax, ws_bsum,
                                         ws_maxf, ws_rsum, ws_bar,
                                         out_pri, out_nrm, n);
    }
}

// Round 9
// 33.779 us; speedup vs baseline: 7.5885x; 7.5885x over previous
//
#include <hip/hip_runtime.h>

#define BSEG   64
#define LATENT 256
#define NB     2048            // grid for both streaming passes
#define ITERS  2               // 1M float4 / (NB*256), guarded
#define SCALE_F   2097152.0f   // 2^21 fixed-point (e <= 1; 512 elems/slot -> <=2^30)
#define INV_SCALE 4.76837158203125e-7   // 2^-21
#define ENC_NEG_INF 0x007FFFFFu         // enc_f32(-INFINITY)

typedef float vfloat4 __attribute__((ext_vector_type(4)));  // clang-native for nontemporal

// Monotone order-preserving f32 -> u32 encoding (for native integer atomicMax).
__device__ __forceinline__ unsigned enc_f32(float x) {
    unsigned u = __float_as_uint(x);
    return (u & 0x80000000u) ? ~u : (u | 0x80000000u);
}
__device__ __forceinline__ float dec_f32(unsigned e) {
    unsigned u = (e & 0x80000000u) ? (e & 0x7FFFFFFFu) : ~e;
    return __uint_as_float(u);
}

// A: uncertainty[b] = 128*log(2*pi*e) + sum_k log(std)
__global__ __launch_bounds__(256) void k_unc(const float* __restrict__ pstd,
                                             float* __restrict__ unc,
                                             float* __restrict__ out_unc) {
    int b = blockIdx.x;
    float v = logf(pstd[b * LATENT + threadIdx.x]);
#pragma unroll
    for (int off = 32; off > 0; off >>= 1) v += __shfl_down(v, off, 64);
    __shared__ float part[4];
    int lane = threadIdx.x & 63, wv = threadIdx.x >> 6;
    if (lane == 0) part[wv] = v;
    __syncthreads();
    if (threadIdx.x == 0) {
        float s = part[0] + part[1] + part[2] + part[3];
        float u = 128.0f * 2.83787706640934548f + s;
        unc[b]     = u;
        out_unc[b] = u;
    }
}

// Pass 1: priority (+u8 sidecar) + per-block online-softmax partials.
// All LDS atomics are no-return (ds_max_u32 / ds_add_u32): fire-and-forget.
__global__ __launch_bounds__(256, 8) void k_pass1(
    const float* __restrict__ coh, const int* __restrict__ batch,
    const float* __restrict__ unc,
    float* __restrict__ bmax_t,          // [BSEG][NB] transposed block maxima
    float* __restrict__ bsum_t,          // [BSEG][NB] transposed block sums
    unsigned char* __restrict__ b8,      // optional u8 batch sidecar
    float* __restrict__ pri, int n, int use8) {
    __shared__ float    unc_s[BSEG];
    __shared__ unsigned max_s[4][BSEG];
    __shared__ unsigned sum_s[4][BSEG];  // u32 fixed-point 2^21
    __shared__ float m_s[BSEG];

    int t = threadIdx.x, wv = t >> 6;
    if (t < BSEG) {
        unc_s[t] = unc[t];
#pragma unroll
        for (int w = 0; w < 4; ++w) { max_s[w][t] = ENC_NEG_INF; sum_s[w][t] = 0u; }
    }
    __syncthreads();

    int gid = blockIdx.x * 256 + t;
    int nv  = n >> 2;

    // ---- priority + per-block max (unconditional no-return atomics) ----
    float4 pr[ITERS];
    int4   bi[ITERS];
#pragma unroll
    for (int u = 0; u < ITERS; ++u) {
        int i = gid + u * (NB * 256);
        if (i < nv) {
            float4 cv = ((const float4*)coh)[i];
            int4   bv = ((const int4*)batch)[i];
            float4 pv;
            pv.x = cv.x * unc_s[bv.x];
            pv.y = cv.y * unc_s[bv.y];
            pv.z = cv.z * unc_s[bv.z];
            pv.w = cv.w * unc_s[bv.w];
            pr[u] = pv; bi[u] = bv;
            ((float4*)pri)[i] = pv;
            if (use8)
                ((uchar4*)b8)[i] = make_uchar4((unsigned char)bv.x, (unsigned char)bv.y,
                                               (unsigned char)bv.z, (unsigned char)bv.w);
            atomicMax(&max_s[wv][bv.x], enc_f32(pv.x));
            atomicMax(&max_s[wv][bv.y], enc_f32(pv.y));
            atomicMax(&max_s[wv][bv.z], enc_f32(pv.z));
            atomicMax(&max_s[wv][bv.w], enc_f32(pv.w));
        } else {
            bi[u].x = -1;
        }
    }
    // scalar tail (n % 4), block 0 only
    float p_t = 0.0f; int b_t = -1;
    if (blockIdx.x == 0) {
        int rem = n - (nv << 2);
        if (t < rem) {
            int i = (nv << 2) + t;
            b_t = batch[i];
            p_t = coh[i] * unc_s[b_t];
            pri[i] = p_t;
            if (use8) b8[i] = (unsigned char)b_t;
            atomicMax(&max_s[wv][b_t], enc_f32(p_t));
        }
    }
    __syncthreads();
    if (t < BSEG) {
        unsigned m = max(max(max_s[0][t], max_s[1][t]), max(max_s[2][t], max_s[3][t]));
        float mf = dec_f32(m);
        m_s[t] = mf;
        bmax_t[t * NB + blockIdx.x] = mf;
    }
    __syncthreads();

    // ---- replay from registers: partial sums exp(p - m_blk), u32 2^21 ----
    // bound: <=512 elems/wave-slot (+3 tail) * 2^21 * e<=1 < 2^31.
#pragma unroll
    for (int u = 0; u < ITERS; ++u) {
        if (bi[u].x >= 0) {
            int4 bv = bi[u]; float4 pv = pr[u];
            atomicAdd(&sum_s[wv][bv.x], (unsigned)(expf(pv.x - m_s[bv.x]) * SCALE_F));
            atomicAdd(&sum_s[wv][bv.y], (unsigned)(expf(pv.y - m_s[bv.y]) * SCALE_F));
            atomicAdd(&sum_s[wv][bv.z], (unsigned)(expf(pv.z - m_s[bv.z]) * SCALE_F));
            atomicAdd(&sum_s[wv][bv.w], (unsigned)(expf(pv.w - m_s[bv.w]) * SCALE_F));
        }
    }
    if (b_t >= 0)
        atomicAdd(&sum_s[wv][b_t], (unsigned)(expf(p_t - m_s[b_t]) * SCALE_F));
    __syncthreads();
    if (t < BSEG) {
        unsigned long long tot = (unsigned long long)sum_s[0][t] + sum_s[1][t]
                               + (unsigned long long)sum_s[2][t] + sum_s[3][t];
        bsum_t[t * NB + blockIdx.x] = (float)((double)tot * INV_SCALE);
    }
}

// Combine: block s merges NB partials -> global max + reciprocal sum.
__global__ __launch_bounds__(256) void k_combine(const float* __restrict__ bmax_t,
                                                 const float* __restrict__ bsum_t,
                                                 float* __restrict__ maxf,
                                                 float* __restrict__ rsum) {
    int s = blockIdx.x, t = threadIdx.x;
    const float* bm = bmax_t + s * NB;
    const float* bs = bsum_t + s * NB;
    float m = -INFINITY;
    for (int i = t; i < NB; i += 256) m = fmaxf(m, bm[i]);
#pragma unroll
    for (int off = 32; off > 0; off >>= 1) m = fmaxf(m, __shfl_down(m, off, 64));
    __shared__ float part[4];
    if ((t & 63) == 0) part[t >> 6] = m;
    __syncthreads();
    float m_g = fmaxf(fmaxf(part[0], part[1]), fmaxf(part[2], part[3]));
    double acc = 0.0;
    for (int i = t; i < NB; i += 256) {
        float d = bm[i] - m_g;
        if (d < -100.0f) d = -100.0f;   // -inf-(-inf) guard; bs=0 there
        acc += (double)bs[i] * (double)expf(d);
    }
#pragma unroll
    for (int off = 32; off > 0; off >>= 1) acc += __shfl_down(acc, off, 64);
    __shared__ double part2[4];
    if ((t & 63) == 0) part2[t >> 6] = acc;
    __syncthreads();
    if (t == 0) {
        double tot = part2[0] + part2[1] + part2[2] + part2[3];
        maxf[s] = m_g;
        rsum[s] = (tot > 0.0) ? (float)(1.0 / tot) : 0.0f;
    }
}

// Pass 2: normalized = exp(pri - maxf[b]) * rsum[b]; nontemporal store.
__global__ __launch_bounds__(256, 8) void k_pass2(
    const float* __restrict__ pri, const int* __restrict__ batch,
    const unsigned char* __restrict__ b8,
    const float* __restrict__ maxf, const float* __restrict__ rsum,
    float* __restrict__ nrm, int n, int use8) {
    __shared__ float m_s[BSEG];
    __shared__ float r_s[BSEG];
    int t = threadIdx.x;
    if (t < BSEG) { m_s[t] = maxf[t]; r_s[t] = rsum[t]; }
    __syncthreads();
    int gid = blockIdx.x * 256 + t;
    int gstride = NB * 256;
    int nv = n >> 2;
    if (use8) {
        for (int i = gid; i < nv; i += gstride) {
            float4 pv = ((const float4*)pri)[i];
            uchar4 bv = ((const uchar4*)b8)[i];
            vfloat4 ov;
            ov.x = expf(pv.x - m_s[bv.x]) * r_s[bv.x];
            ov.y = expf(pv.y - m_s[bv.y]) * r_s[bv.y];
            ov.z = expf(pv.z - m_s[bv.z]) * r_s[bv.z];
            ov.w = expf(pv.w - m_s[bv.w]) * r_s[bv.w];
            __builtin_nontemporal_store(ov, (vfloat4*)nrm + i);
        }
    } else {
        for (int i = gid; i < nv; i += gstride) {
            float4 pv = ((const float4*)pri)[i];
            int4   bv = ((const int4*)batch)[i];
            vfloat4 ov;
            ov.x = expf(pv.x - m_s[bv.x]) * r_s[bv.x];
            ov.y = expf(pv.y - m_s[bv.y]) * r_s[bv.y];
            ov.z = expf(pv.z - m_s[bv.z]) * r_s[bv.z];
            ov.w = expf(pv.w - m_s[bv.w]) * r_s[bv.w];
            __builtin_nontemporal_store(ov, (vfloat4*)nrm + i);
        }
    }
    for (int i = (nv << 2) + gid; i < n; i += gstride) {
        int b = batch[i];
        nrm[i] = expf(pri[i] - m_s[b]) * r_s[b];
    }
}

extern "C" void kernel_launch(void* const* d_in, const int* in_sizes, int n_in,
                              void* d_out, int out_size, void* d_ws, size_t ws_size,
                              hipStream_t stream) {
    const float* coh   = (const float*)d_in[0];
    // d_in[1] = posterior_mean (unused by the reference outputs)
    const float* pstd  = (const float*)d_in[2];
    const int*   batch = (const int*)d_in[3];
    int n = in_sizes[0];

    float* out     = (float*)d_out;
    float* out_pri = out;
    float* out_nrm = out + n;
    float* out_unc = out + 2 * (size_t)n;

    // ws layout (bytes):
    // [0,256)    unc
    // [256,512)  maxf
    // [512,768)  rsum
    // [1024, +NB*64*4)       bmax_t (transposed [seg][block])
    // [+NB*64*4, +2*NB*64*4) bsum_t
    // [base8, base8+n)       optional u8 batch sidecar
    size_t part_bytes = (size_t)NB * BSEG * 4;
    size_t base8      = 1024 + 2 * part_bytes;
    int    use8       = (ws_size >= base8 + (size_t)n) ? 1 : 0;

    float*         ws_unc  = (float*)d_ws;
    float*         ws_maxf = (float*)((char*)d_ws + 256);
    float*         ws_rsum = (float*)((char*)d_ws + 512);
    float*         ws_bmax = (float*)((char*)d_ws + 1024);
    float*         ws_bsum = (float*)((char*)d_ws + 1024 + part_bytes);
    unsigned char* ws_b8   = (unsigned char*)d_ws + base8;

    k_unc    <<<BSEG, 256, 0, stream>>>(pstd, ws_unc, out_unc);
    k_pass1  <<<NB,   256, 0, stream>>>(coh, batch, ws_unc, ws_bmax, ws_bsum,
                                        ws_b8, out_pri, n, use8);
    k_combine<<<BSEG, 256, 0, stream>>>(ws_bmax, ws_bsum, ws_maxf, ws_rsum);
    k_pass2  <<<NB,   256, 0, stream>>>(out_pri, batch, ws_b8, ws_maxf, ws_rsum,
                                        out_nrm, n, use8);
}